// Round 2
// baseline (533.751 us; speedup 1.0000x reference)
//
#include <hip/hip_runtime.h>

#define IN_DIM 128
#define OUT_DIM 64
#define REL_DIM 32
#define NEG_SLOPE 0.01f

// ---------- kernel 1: tiny constants: wra3[32] = W_r @ a3, c4 = W_s.a4, c5 = W_t.a5
__global__ void k_consts(const float* __restrict__ W_r, const float* __restrict__ W_s,
                         const float* __restrict__ W_t, const float* __restrict__ a,
                         float* __restrict__ consts /*34 floats*/) {
    int t = threadIdx.x;
    if (t < REL_DIM) {
        const float* a3 = a + 2 * OUT_DIM;
        float acc = 0.f;
        for (int d = 0; d < OUT_DIM; ++d) acc += W_r[t * OUT_DIM + d] * a3[d];
        consts[t] = acc;
    } else if (t == 32) {
        float acc = 0.f;
        for (int d = 0; d < OUT_DIM; ++d) acc += W_s[d] * a[3 * OUT_DIM + d];
        consts[32] = acc;
    } else if (t == 33) {
        float acc = 0.f;
        for (int d = 0; d < OUT_DIM; ++d) acc += W_t[d] * a[4 * OUT_DIM + d];
        consts[33] = acc;
    }
}

// ---------- kernel 2: z = h @ W_n ; s1[n]=z[n].a1 ; s2[n]=z[n].a2
__global__ __launch_bounds__(256) void k_node(const float* __restrict__ h,
                                              const float* __restrict__ W_n,
                                              const float* __restrict__ a,
                                              float* __restrict__ z,
                                              float* __restrict__ s1,
                                              float* __restrict__ s2, int n) {
    __shared__ float Wn[IN_DIM * OUT_DIM];   // 32 KB
    __shared__ float a1s[OUT_DIM], a2s[OUT_DIM];
    for (int i = threadIdx.x; i < IN_DIM * OUT_DIM; i += blockDim.x) Wn[i] = W_n[i];
    if (threadIdx.x < OUT_DIM) {
        a1s[threadIdx.x] = a[threadIdx.x];
        a2s[threadIdx.x] = a[OUT_DIM + threadIdx.x];
    }
    __syncthreads();
    int wave = threadIdx.x >> 6;
    int lane = threadIdx.x & 63;
    int wstride = gridDim.x * 4;
    for (int row = blockIdx.x * 4 + wave; row < n; row += wstride) {
        const float* hr = h + (size_t)row * IN_DIM;
        float acc = 0.f;
        #pragma unroll 8
        for (int k = 0; k < IN_DIM; ++k) acc = fmaf(hr[k], Wn[k * OUT_DIM + lane], acc);
        z[(size_t)row * OUT_DIM + lane] = acc;
        float v1 = acc * a1s[lane];
        float v2 = acc * a2s[lane];
        #pragma unroll
        for (int o = 32; o > 0; o >>= 1) {
            v1 += __shfl_xor(v1, o, 64);
            v2 += __shfl_xor(v2, o, 64);
        }
        if (lane == 0) { s1[row] = v1; s2[row] = v2; }
    }
}

// float -> order-preserving unsigned
__device__ __forceinline__ unsigned f2u(float f) {
    unsigned u = __float_as_uint(f);
    return (u & 0x80000000u) ? ~u : (u | 0x80000000u);
}
__device__ __forceinline__ float u2f(unsigned u) {
    u = (u & 0x80000000u) ? (u & 0x7fffffffu) : ~u;
    return __uint_as_float(u);
}

// ---------- kernel 3: per-edge logit + leaky relu + segment max (atomic)
__global__ __launch_bounds__(256) void k_logit(const float* __restrict__ rel,
                                               const float* __restrict__ score,
                                               const float* __restrict__ ts,
                                               const int* __restrict__ src,
                                               const int* __restrict__ dst,
                                               const float* __restrict__ s1,
                                               const float* __restrict__ s2,
                                               const float* __restrict__ consts,
                                               float* __restrict__ logit,
                                               unsigned* __restrict__ segmax, int E) {
    __shared__ float wra3[REL_DIM];
    __shared__ float c45[2];
    if (threadIdx.x < REL_DIM) wra3[threadIdx.x] = consts[threadIdx.x];
    if (threadIdx.x == 32) c45[0] = consts[32];
    if (threadIdx.x == 33) c45[1] = consts[33];
    __syncthreads();
    for (int e = blockIdx.x * blockDim.x + threadIdx.x; e < E;
         e += gridDim.x * blockDim.x) {
        const float4* r4 = (const float4*)(rel + (size_t)e * REL_DIM);
        float acc = 0.f;
        #pragma unroll
        for (int j = 0; j < REL_DIM / 4; ++j) {
            float4 v = r4[j];
            acc += v.x * wra3[4 * j] + v.y * wra3[4 * j + 1] +
                   v.z * wra3[4 * j + 2] + v.w * wra3[4 * j + 3];
        }
        int s = src[e], d = dst[e];
        float lg = s1[s] + s2[d] + acc + score[e] * c45[0] + ts[e] * c45[1];
        lg = (lg >= 0.f) ? lg : NEG_SLOPE * lg;
        logit[e] = lg;
        atomicMax(segmax + d, f2u(lg));
    }
}

// ---------- kernel 4: ex = exp(logit - segmax[dst]); segment sum (atomic)
__global__ __launch_bounds__(256) void k_ex(const int* __restrict__ dst,
                                            const unsigned* __restrict__ segmax,
                                            float* __restrict__ logit /*in: logit, out: ex*/,
                                            float* __restrict__ segsum, int E) {
    for (int e = blockIdx.x * blockDim.x + threadIdx.x; e < E;
         e += gridDim.x * blockDim.x) {
        int d = dst[e];
        float m = u2f(segmax[d]);
        float ex = expf(logit[e] - m);
        logit[e] = ex;
        atomicAdd(segsum + d, ex);
    }
}

// ---------- kernel 5: h_out[dst] += (ex/segsum[dst]) * z[src]  (one wave per edge)
__global__ __launch_bounds__(256) void k_scatter(const int* __restrict__ src,
                                                 const int* __restrict__ dst,
                                                 const float* __restrict__ ex,
                                                 const float* __restrict__ segsum,
                                                 const float* __restrict__ z,
                                                 float* __restrict__ out, int E) {
    int lane = threadIdx.x & 63;
    int wave = (blockIdx.x * blockDim.x + threadIdx.x) >> 6;
    int nwaves = (gridDim.x * blockDim.x) >> 6;
    for (int e = wave; e < E; e += nwaves) {
        int s = src[e], d = dst[e];
        float alpha = ex[e] / segsum[d];
        atomicAdd(out + (size_t)d * OUT_DIM + lane,
                  alpha * z[(size_t)s * OUT_DIM + lane]);
    }
}

extern "C" void kernel_launch(void* const* d_in, const int* in_sizes, int n_in,
                              void* d_out, int out_size, void* d_ws, size_t ws_size,
                              hipStream_t stream) {
    const float* h         = (const float*)d_in[0];
    const float* relation  = (const float*)d_in[1];
    const float* score     = (const float*)d_in[2];
    const float* timestamp = (const float*)d_in[3];
    const int*   src       = (const int*)d_in[4];
    const int*   dst       = (const int*)d_in[5];
    const float* W_n       = (const float*)d_in[6];
    const float* W_r       = (const float*)d_in[7];
    const float* W_s       = (const float*)d_in[8];
    const float* W_t       = (const float*)d_in[9];
    const float* a         = (const float*)d_in[10];

    int n = in_sizes[0] / IN_DIM;   // 50000
    int E = in_sizes[4];            // 800000

    // workspace layout (floats)
    float* ws      = (float*)d_ws;
    float* z       = ws;                                 // n*64
    float* s1      = z + (size_t)n * OUT_DIM;            // n
    float* s2      = s1 + n;                             // n
    unsigned* smax = (unsigned*)(s2 + n);                // n
    float* ssum    = (float*)(smax + n);                 // n
    float* exb     = ssum + n;                           // E (logit, then ex in-place)
    float* consts  = exb + E;                            // 34

    float* out = (float*)d_out;

    // init: segmax=0 (below every f2u of a real float), segsum=0, out=0
    hipMemsetAsync(smax, 0, (size_t)n * 2 * sizeof(float), stream);
    hipMemsetAsync(out, 0, (size_t)n * OUT_DIM * sizeof(float), stream);

    k_consts<<<1, 64, 0, stream>>>(W_r, W_s, W_t, a, consts);
    k_node<<<512, 256, 0, stream>>>(h, W_n, a, z, s1, s2, n);
    k_logit<<<2048, 256, 0, stream>>>(relation, score, timestamp, src, dst,
                                      s1, s2, consts, exb, smax, E);
    k_ex<<<2048, 256, 0, stream>>>(dst, smax, exb, ssum, E);
    k_scatter<<<4096, 256, 0, stream>>>(src, dst, exb, ssum, z, out, E);
}

// Round 3
// 453.332 us; speedup vs baseline: 1.1774x; 1.1774x over previous
//
#include <hip/hip_runtime.h>

#define IN_DIM 128
#define OUT_DIM 64
#define REL_DIM 32
#define NEG_SLOPE 0.01f

// ---------- kernel 1: tiny constants: wra3[32] = W_r @ a3, c4 = W_s.a4, c5 = W_t.a5
__global__ void k_consts(const float* __restrict__ W_r, const float* __restrict__ W_s,
                         const float* __restrict__ W_t, const float* __restrict__ a,
                         float* __restrict__ consts /*34 floats*/) {
    int t = threadIdx.x;
    if (t < REL_DIM) {
        const float* a3 = a + 2 * OUT_DIM;
        float acc = 0.f;
        for (int d = 0; d < OUT_DIM; ++d) acc += W_r[t * OUT_DIM + d] * a3[d];
        consts[t] = acc;
    } else if (t == 32) {
        float acc = 0.f;
        for (int d = 0; d < OUT_DIM; ++d) acc += W_s[d] * a[3 * OUT_DIM + d];
        consts[32] = acc;
    } else if (t == 33) {
        float acc = 0.f;
        for (int d = 0; d < OUT_DIM; ++d) acc += W_t[d] * a[4 * OUT_DIM + d];
        consts[33] = acc;
    }
}

// ---------- kernel 2: z = h @ W_n ; s1[n]=z[n].a1 ; s2[n]=z[n].a2
__global__ __launch_bounds__(256) void k_node(const float* __restrict__ h,
                                              const float* __restrict__ W_n,
                                              const float* __restrict__ a,
                                              float* __restrict__ z,
                                              float* __restrict__ s1,
                                              float* __restrict__ s2, int n) {
    __shared__ float Wn[IN_DIM * OUT_DIM];   // 32 KB
    __shared__ float a1s[OUT_DIM], a2s[OUT_DIM];
    for (int i = threadIdx.x; i < IN_DIM * OUT_DIM; i += blockDim.x) Wn[i] = W_n[i];
    if (threadIdx.x < OUT_DIM) {
        a1s[threadIdx.x] = a[threadIdx.x];
        a2s[threadIdx.x] = a[OUT_DIM + threadIdx.x];
    }
    __syncthreads();
    int wave = threadIdx.x >> 6;
    int lane = threadIdx.x & 63;
    int wstride = gridDim.x * 4;
    for (int row = blockIdx.x * 4 + wave; row < n; row += wstride) {
        const float* hr = h + (size_t)row * IN_DIM;
        float acc = 0.f;
        #pragma unroll 8
        for (int k = 0; k < IN_DIM; ++k) acc = fmaf(hr[k], Wn[k * OUT_DIM + lane], acc);
        z[(size_t)row * OUT_DIM + lane] = acc;
        float v1 = acc * a1s[lane];
        float v2 = acc * a2s[lane];
        #pragma unroll
        for (int o = 32; o > 0; o >>= 1) {
            v1 += __shfl_xor(v1, o, 64);
            v2 += __shfl_xor(v2, o, 64);
        }
        if (lane == 0) { s1[row] = v1; s2[row] = v2; }
    }
}

// ---------- kernel 3: per-edge logit + leaky relu + degree histogram (no atomicMax)
__global__ __launch_bounds__(256) void k_logit(const float* __restrict__ rel,
                                               const float* __restrict__ score,
                                               const float* __restrict__ ts,
                                               const int* __restrict__ src,
                                               const int* __restrict__ dst,
                                               const float* __restrict__ s1,
                                               const float* __restrict__ s2,
                                               const float* __restrict__ consts,
                                               float* __restrict__ logit,
                                               int* __restrict__ deg, int E) {
    __shared__ float wra3[REL_DIM];
    __shared__ float c45[2];
    if (threadIdx.x < REL_DIM) wra3[threadIdx.x] = consts[threadIdx.x];
    if (threadIdx.x == 32) c45[0] = consts[32];
    if (threadIdx.x == 33) c45[1] = consts[33];
    __syncthreads();
    for (int e = blockIdx.x * blockDim.x + threadIdx.x; e < E;
         e += gridDim.x * blockDim.x) {
        const float4* r4 = (const float4*)(rel + (size_t)e * REL_DIM);
        float acc = 0.f;
        #pragma unroll
        for (int j = 0; j < REL_DIM / 4; ++j) {
            float4 v = r4[j];
            acc += v.x * wra3[4 * j] + v.y * wra3[4 * j + 1] +
                   v.z * wra3[4 * j + 2] + v.w * wra3[4 * j + 3];
        }
        int s = src[e], d = dst[e];
        float lg = s1[s] + s2[d] + acc + score[e] * c45[0] + ts[e] * c45[1];
        lg = (lg >= 0.f) ? lg : NEG_SLOPE * lg;
        logit[e] = lg;
        atomicAdd(deg + d, 1);
    }
}

// ---------- scan kernels: exclusive prefix sum of deg[0..n) -> off, cnt; off[n]=E
__global__ __launch_bounds__(256) void k_scan1(const int* __restrict__ deg,
                                               int* __restrict__ incl,
                                               int* __restrict__ partial, int n) {
    __shared__ int tmp[256];
    int i = blockIdx.x * 256 + threadIdx.x;
    int v = (i < n) ? deg[i] : 0;
    tmp[threadIdx.x] = v;
    __syncthreads();
    #pragma unroll
    for (int o = 1; o < 256; o <<= 1) {
        int t = (threadIdx.x >= o) ? tmp[threadIdx.x - o] : 0;
        __syncthreads();
        tmp[threadIdx.x] += t;
        __syncthreads();
    }
    if (i < n) incl[i] = tmp[threadIdx.x];
    if (threadIdx.x == 255) partial[blockIdx.x] = tmp[255];
}

__global__ __launch_bounds__(256) void k_scan2(int* __restrict__ partial, int nb) {
    __shared__ int tmp[256];
    int v = (threadIdx.x < nb) ? partial[threadIdx.x] : 0;
    tmp[threadIdx.x] = v;
    __syncthreads();
    #pragma unroll
    for (int o = 1; o < 256; o <<= 1) {
        int t = (threadIdx.x >= o) ? tmp[threadIdx.x - o] : 0;
        __syncthreads();
        tmp[threadIdx.x] += t;
        __syncthreads();
    }
    if (threadIdx.x < nb) partial[threadIdx.x] = tmp[threadIdx.x] - v;  // exclusive
}

__global__ __launch_bounds__(256) void k_scan3(const int* __restrict__ deg,
                                               const int* __restrict__ incl,
                                               const int* __restrict__ partial,
                                               int* __restrict__ off,
                                               int* __restrict__ cnt, int n, int E) {
    int i = blockIdx.x * 256 + threadIdx.x;
    if (i < n) {
        int o = incl[i] - deg[i] + partial[i >> 8];
        off[i] = o;
        cnt[i] = o;
    }
    if (i == 0) off[n] = E;
}

// ---------- fill: permute src + logit into dst-grouped order
__global__ __launch_bounds__(256) void k_fill(const int* __restrict__ src,
                                              const int* __restrict__ dst,
                                              const float* __restrict__ logit,
                                              int* __restrict__ cnt,
                                              int* __restrict__ psrc,
                                              float* __restrict__ plog, int E) {
    for (int e = blockIdx.x * blockDim.x + threadIdx.x; e < E;
         e += gridDim.x * blockDim.x) {
        int d = dst[e];
        int pos = atomicAdd(cnt + d, 1);
        psrc[pos] = src[e];
        plog[pos] = logit[e];
    }
}

// ---------- out: one wave per node, softmax + weighted gather, non-atomic store
__global__ __launch_bounds__(256) void k_out(const int* __restrict__ off,
                                             const int* __restrict__ psrc,
                                             const float* __restrict__ plog,
                                             const float* __restrict__ z,
                                             float* __restrict__ out, int n) {
    int lane = threadIdx.x & 63;
    int wave = (blockIdx.x * blockDim.x + threadIdx.x) >> 6;
    int nwaves = (gridDim.x * blockDim.x) >> 6;
    for (int node = wave; node < n; node += nwaves) {
        int start = off[node], end = off[node + 1];
        // phase A: max and sum-exp, lanes parallel over edges
        float m = -3.4e38f;
        for (int j = start + lane; j < end; j += 64) m = fmaxf(m, plog[j]);
        #pragma unroll
        for (int o = 32; o > 0; o >>= 1) m = fmaxf(m, __shfl_xor(m, o, 64));
        float ssum = 0.f;
        for (int j = start + lane; j < end; j += 64) ssum += __expf(plog[j] - m);
        #pragma unroll
        for (int o = 32; o > 0; o >>= 1) ssum += __shfl_xor(ssum, o, 64);
        // phase B: lane = output dim, serial over edges
        float acc = 0.f;
        if (end > start) {
            float inv = 1.0f / ssum;
            for (int j = start; j < end; ++j) {
                float w = __expf(plog[j] - m) * inv;
                acc = fmaf(w, z[(size_t)psrc[j] * OUT_DIM + lane], acc);
            }
        }
        out[(size_t)node * OUT_DIM + lane] = acc;
    }
}

extern "C" void kernel_launch(void* const* d_in, const int* in_sizes, int n_in,
                              void* d_out, int out_size, void* d_ws, size_t ws_size,
                              hipStream_t stream) {
    const float* h         = (const float*)d_in[0];
    const float* relation  = (const float*)d_in[1];
    const float* score     = (const float*)d_in[2];
    const float* timestamp = (const float*)d_in[3];
    const int*   src       = (const int*)d_in[4];
    const int*   dst       = (const int*)d_in[5];
    const float* W_n       = (const float*)d_in[6];
    const float* W_r       = (const float*)d_in[7];
    const float* W_s       = (const float*)d_in[8];
    const float* W_t       = (const float*)d_in[9];
    const float* a         = (const float*)d_in[10];

    int n = in_sizes[0] / IN_DIM;   // 50000
    int E = in_sizes[4];            // 800000
    int nb1 = (n + 255) / 256;      // 196 scan blocks

    // workspace layout
    float* ws      = (float*)d_ws;
    float* z       = ws;                                  // n*64
    float* s1      = z + (size_t)n * OUT_DIM;             // n
    float* s2      = s1 + n;                              // n
    float* logit   = s2 + n;                              // E
    float* plog    = logit + E;                           // E
    float* consts  = plog + E;                            // 34 (pad to 64)
    int*   psrc    = (int*)(consts + 64);                 // E
    int*   deg     = psrc + E;                            // n
    int*   incl    = deg + n;                             // n
    int*   off     = incl + n;                            // n+1
    int*   cnt     = off + n + 1;                         // n
    int*   partial = cnt + n;                             // nb1 (<=256)

    float* out = (float*)d_out;

    hipMemsetAsync(deg, 0, (size_t)n * sizeof(int), stream);

    k_consts<<<1, 64, 0, stream>>>(W_r, W_s, W_t, a, consts);
    k_node<<<512, 256, 0, stream>>>(h, W_n, a, z, s1, s2, n);
    k_logit<<<2048, 256, 0, stream>>>(relation, score, timestamp, src, dst,
                                      s1, s2, consts, logit, deg, E);
    k_scan1<<<nb1, 256, 0, stream>>>(deg, incl, partial, n);
    k_scan2<<<1, 256, 0, stream>>>(partial, nb1);
    k_scan3<<<nb1, 256, 0, stream>>>(deg, incl, partial, off, cnt, n, E);
    k_fill<<<2048, 256, 0, stream>>>(src, dst, logit, cnt, psrc, plog, E);
    k_out<<<(n + 3) / 4, 256, 0, stream>>>(off, psrc, plog, z, out, n);
}

// Round 4
// 375.062 us; speedup vs baseline: 1.4231x; 1.2087x over previous
//
#include <hip/hip_runtime.h>

#define IN_DIM 128
#define OUT_DIM 64
#define REL_DIM 32
#define NEG_SLOPE 0.01f

// ---------- kernel 1: tiny constants: wra3[32] = W_r @ a3, c4 = W_s.a4, c5 = W_t.a5
__global__ void k_consts(const float* __restrict__ W_r, const float* __restrict__ W_s,
                         const float* __restrict__ W_t, const float* __restrict__ a,
                         float* __restrict__ consts /*34 floats*/) {
    int t = threadIdx.x;
    if (t < REL_DIM) {
        const float* a3 = a + 2 * OUT_DIM;
        float acc = 0.f;
        for (int d = 0; d < OUT_DIM; ++d) acc += W_r[t * OUT_DIM + d] * a3[d];
        consts[t] = acc;
    } else if (t == 32) {
        float acc = 0.f;
        for (int d = 0; d < OUT_DIM; ++d) acc += W_s[d] * a[3 * OUT_DIM + d];
        consts[32] = acc;
    } else if (t == 33) {
        float acc = 0.f;
        for (int d = 0; d < OUT_DIM; ++d) acc += W_t[d] * a[4 * OUT_DIM + d];
        consts[33] = acc;
    }
}

// ---------- kernel 2: z = h @ W_n ; s1[n]=z[n].a1 ; s2[n]=z[n].a2
// block = 256 threads = 4 waves; block covers 64 rows; wave w covers cols [16w,16w+16)
// lane = row. h tile staged transposed in LDS (pad 65 -> conflict-free).
// W reads are wave-uniform -> scalar loads. 16 independent accumulators = ILP.
__global__ __launch_bounds__(256) void k_node(const float* __restrict__ h,
                                              const float* __restrict__ W_n,
                                              const float* __restrict__ a,
                                              float* __restrict__ z,
                                              float* __restrict__ s1,
                                              float* __restrict__ s2, int n) {
    __shared__ float hs[IN_DIM * 65];          // hs[k][r] at k*65+r, 33280 B
    __shared__ float s1p[4][64], s2p[4][64];
    int base = blockIdx.x * 64;

    // stage: 64 rows x 128 cols, float4 global reads, transposed scalar LDS writes
    for (int i = threadIdx.x; i < 64 * 32; i += 256) {
        int r = i >> 5;            // row in tile
        int c4 = i & 31;           // float4 index along k
        float4 v = make_float4(0.f, 0.f, 0.f, 0.f);
        if (base + r < n) v = ((const float4*)(h + (size_t)(base + r) * IN_DIM))[c4];
        int k0 = c4 * 4;
        hs[(k0 + 0) * 65 + r] = v.x;
        hs[(k0 + 1) * 65 + r] = v.y;
        hs[(k0 + 2) * 65 + r] = v.z;
        hs[(k0 + 3) * 65 + r] = v.w;
    }
    __syncthreads();

    int lane = threadIdx.x & 63;
    int w = __builtin_amdgcn_readfirstlane(threadIdx.x >> 6);  // wave id, uniform
    int c0 = w * 16;
    int row = base + lane;

    float acc[16];
    #pragma unroll
    for (int j = 0; j < 16; ++j) acc[j] = 0.f;

    const float* __restrict__ Wslice = W_n + c0;   // uniform pointer
    #pragma unroll 4
    for (int k = 0; k < IN_DIM; ++k) {
        float hv = hs[k * 65 + lane];
        const float* __restrict__ Wr = Wslice + k * OUT_DIM;  // uniform
        #pragma unroll
        for (int j = 0; j < 16; ++j) acc[j] = fmaf(hv, Wr[j], acc[j]);
    }

    // s1/s2 partials for this wave's 16-col slice
    float p1 = 0.f, p2 = 0.f;
    #pragma unroll
    for (int j = 0; j < 16; ++j) {
        p1 = fmaf(acc[j], a[c0 + j], p1);
        p2 = fmaf(acc[j], a[OUT_DIM + c0 + j], p2);
    }
    s1p[w][lane] = p1;
    s2p[w][lane] = p2;

    if (row < n) {
        float4* zp = (float4*)(z + (size_t)row * OUT_DIM + c0);
        zp[0] = make_float4(acc[0], acc[1], acc[2], acc[3]);
        zp[1] = make_float4(acc[4], acc[5], acc[6], acc[7]);
        zp[2] = make_float4(acc[8], acc[9], acc[10], acc[11]);
        zp[3] = make_float4(acc[12], acc[13], acc[14], acc[15]);
    }
    __syncthreads();
    if (threadIdx.x < 64 && base + (int)threadIdx.x < n) {
        int l = threadIdx.x;
        s1[base + l] = s1p[0][l] + s1p[1][l] + s1p[2][l] + s1p[3][l];
        s2[base + l] = s2p[0][l] + s2p[1][l] + s2p[2][l] + s2p[3][l];
    }
}

// ---------- kernel 3: per-edge logit + leaky relu + degree histogram
__global__ __launch_bounds__(256) void k_logit(const float* __restrict__ rel,
                                               const float* __restrict__ score,
                                               const float* __restrict__ ts,
                                               const int* __restrict__ src,
                                               const int* __restrict__ dst,
                                               const float* __restrict__ s1,
                                               const float* __restrict__ s2,
                                               const float* __restrict__ consts,
                                               float* __restrict__ logit,
                                               int* __restrict__ deg, int E) {
    __shared__ float wra3[REL_DIM];
    __shared__ float c45[2];
    if (threadIdx.x < REL_DIM) wra3[threadIdx.x] = consts[threadIdx.x];
    if (threadIdx.x == 32) c45[0] = consts[32];
    if (threadIdx.x == 33) c45[1] = consts[33];
    __syncthreads();
    for (int e = blockIdx.x * blockDim.x + threadIdx.x; e < E;
         e += gridDim.x * blockDim.x) {
        const float4* r4 = (const float4*)(rel + (size_t)e * REL_DIM);
        float acc = 0.f;
        #pragma unroll
        for (int j = 0; j < REL_DIM / 4; ++j) {
            float4 v = r4[j];
            acc += v.x * wra3[4 * j] + v.y * wra3[4 * j + 1] +
                   v.z * wra3[4 * j + 2] + v.w * wra3[4 * j + 3];
        }
        int s = src[e], d = dst[e];
        float lg = s1[s] + s2[d] + acc + score[e] * c45[0] + ts[e] * c45[1];
        lg = (lg >= 0.f) ? lg : NEG_SLOPE * lg;
        logit[e] = lg;
        atomicAdd(deg + d, 1);
    }
}

// ---------- scan kernels: exclusive prefix sum of deg[0..n) -> off, cnt; off[n]=E
__global__ __launch_bounds__(256) void k_scan1(const int* __restrict__ deg,
                                               int* __restrict__ incl,
                                               int* __restrict__ partial, int n) {
    __shared__ int tmp[256];
    int i = blockIdx.x * 256 + threadIdx.x;
    int v = (i < n) ? deg[i] : 0;
    tmp[threadIdx.x] = v;
    __syncthreads();
    #pragma unroll
    for (int o = 1; o < 256; o <<= 1) {
        int t = (threadIdx.x >= o) ? tmp[threadIdx.x - o] : 0;
        __syncthreads();
        tmp[threadIdx.x] += t;
        __syncthreads();
    }
    if (i < n) incl[i] = tmp[threadIdx.x];
    if (threadIdx.x == 255) partial[blockIdx.x] = tmp[255];
}

__global__ __launch_bounds__(256) void k_scan2(int* __restrict__ partial, int nb) {
    __shared__ int tmp[256];
    int v = (threadIdx.x < nb) ? partial[threadIdx.x] : 0;
    tmp[threadIdx.x] = v;
    __syncthreads();
    #pragma unroll
    for (int o = 1; o < 256; o <<= 1) {
        int t = (threadIdx.x >= o) ? tmp[threadIdx.x - o] : 0;
        __syncthreads();
        tmp[threadIdx.x] += t;
        __syncthreads();
    }
    if (threadIdx.x < nb) partial[threadIdx.x] = tmp[threadIdx.x] - v;  // exclusive
}

__global__ __launch_bounds__(256) void k_scan3(const int* __restrict__ deg,
                                               const int* __restrict__ incl,
                                               const int* __restrict__ partial,
                                               int* __restrict__ off,
                                               int* __restrict__ cnt, int n, int E) {
    int i = blockIdx.x * 256 + threadIdx.x;
    if (i < n) {
        int o = incl[i] - deg[i] + partial[i >> 8];
        off[i] = o;
        cnt[i] = o;
    }
    if (i == 0) off[n] = E;
}

// ---------- fill: permute src + logit into dst-grouped order
__global__ __launch_bounds__(256) void k_fill(const int* __restrict__ src,
                                              const int* __restrict__ dst,
                                              const float* __restrict__ logit,
                                              int* __restrict__ cnt,
                                              int* __restrict__ psrc,
                                              float* __restrict__ plog, int E) {
    for (int e = blockIdx.x * blockDim.x + threadIdx.x; e < E;
         e += gridDim.x * blockDim.x) {
        int d = dst[e];
        int pos = atomicAdd(cnt + d, 1);
        psrc[pos] = src[e];
        plog[pos] = logit[e];
    }
}

// ---------- out: one wave per node, softmax + weighted gather, non-atomic store
__global__ __launch_bounds__(256) void k_out(const int* __restrict__ off,
                                             const int* __restrict__ psrc,
                                             const float* __restrict__ plog,
                                             const float* __restrict__ z,
                                             float* __restrict__ out, int n) {
    int lane = threadIdx.x & 63;
    int wave = (blockIdx.x * blockDim.x + threadIdx.x) >> 6;
    int nwaves = (gridDim.x * blockDim.x) >> 6;
    for (int node = wave; node < n; node += nwaves) {
        int start = off[node], end = off[node + 1];
        // phase A: max and sum-exp, lanes parallel over edges
        float m = -3.4e38f;
        for (int j = start + lane; j < end; j += 64) m = fmaxf(m, plog[j]);
        #pragma unroll
        for (int o = 32; o > 0; o >>= 1) m = fmaxf(m, __shfl_xor(m, o, 64));
        float ssum = 0.f;
        for (int j = start + lane; j < end; j += 64) ssum += __expf(plog[j] - m);
        #pragma unroll
        for (int o = 32; o > 0; o >>= 1) ssum += __shfl_xor(ssum, o, 64);
        // phase B: lane = output dim, serial over edges
        float acc = 0.f;
        if (end > start) {
            float inv = 1.0f / ssum;
            for (int j = start; j < end; ++j) {
                float wgt = __expf(plog[j] - m) * inv;
                acc = fmaf(wgt, z[(size_t)psrc[j] * OUT_DIM + lane], acc);
            }
        }
        out[(size_t)node * OUT_DIM + lane] = acc;
    }
}

extern "C" void kernel_launch(void* const* d_in, const int* in_sizes, int n_in,
                              void* d_out, int out_size, void* d_ws, size_t ws_size,
                              hipStream_t stream) {
    const float* h         = (const float*)d_in[0];
    const float* relation  = (const float*)d_in[1];
    const float* score     = (const float*)d_in[2];
    const float* timestamp = (const float*)d_in[3];
    const int*   src       = (const int*)d_in[4];
    const int*   dst       = (const int*)d_in[5];
    const float* W_n       = (const float*)d_in[6];
    const float* W_r       = (const float*)d_in[7];
    const float* W_s       = (const float*)d_in[8];
    const float* W_t       = (const float*)d_in[9];
    const float* a         = (const float*)d_in[10];

    int n = in_sizes[0] / IN_DIM;   // 50000
    int E = in_sizes[4];            // 800000
    int nb1 = (n + 255) / 256;      // 196 scan blocks

    // workspace layout
    float* ws      = (float*)d_ws;
    float* z       = ws;                                  // n*64
    float* s1      = z + (size_t)n * OUT_DIM;             // n
    float* s2      = s1 + n;                              // n
    float* logit   = s2 + n;                              // E
    float* plog    = logit + E;                           // E
    float* consts  = plog + E;                            // 34 (pad to 64)
    int*   psrc    = (int*)(consts + 64);                 // E
    int*   deg     = psrc + E;                            // n
    int*   incl    = deg + n;                             // n
    int*   off     = incl + n;                            // n+1
    int*   cnt     = off + n + 1;                         // n
    int*   partial = cnt + n;                             // nb1 (<=256)

    float* out = (float*)d_out;

    hipMemsetAsync(deg, 0, (size_t)n * sizeof(int), stream);

    k_consts<<<1, 64, 0, stream>>>(W_r, W_s, W_t, a, consts);
    k_node<<<(n + 63) / 64, 256, 0, stream>>>(h, W_n, a, z, s1, s2, n);
    k_logit<<<2048, 256, 0, stream>>>(relation, score, timestamp, src, dst,
                                      s1, s2, consts, logit, deg, E);
    k_scan1<<<nb1, 256, 0, stream>>>(deg, incl, partial, n);
    k_scan2<<<1, 256, 0, stream>>>(partial, nb1);
    k_scan3<<<nb1, 256, 0, stream>>>(deg, incl, partial, off, cnt, n, E);
    k_fill<<<2048, 256, 0, stream>>>(src, dst, logit, cnt, psrc, plog, E);
    k_out<<<(n + 3) / 4, 256, 0, stream>>>(off, psrc, plog, z, out, n);
}

// Round 5
// 323.946 us; speedup vs baseline: 1.6477x; 1.1578x over previous
//
#include <hip/hip_runtime.h>

#define IN_DIM 128
#define OUT_DIM 64
#define REL_DIM 32
#define NEG_SLOPE 0.01f

// ---------- kernel 1: tiny constants: wra3[32] = W_r @ a3, c4 = W_s.a4, c5 = W_t.a5
__global__ void k_consts(const float* __restrict__ W_r, const float* __restrict__ W_s,
                         const float* __restrict__ W_t, const float* __restrict__ a,
                         float* __restrict__ consts /*34 floats*/) {
    int t = threadIdx.x;
    if (t < REL_DIM) {
        const float* a3 = a + 2 * OUT_DIM;
        float acc = 0.f;
        for (int d = 0; d < OUT_DIM; ++d) acc += W_r[t * OUT_DIM + d] * a3[d];
        consts[t] = acc;
    } else if (t == 32) {
        float acc = 0.f;
        for (int d = 0; d < OUT_DIM; ++d) acc += W_s[d] * a[3 * OUT_DIM + d];
        consts[32] = acc;
    } else if (t == 33) {
        float acc = 0.f;
        for (int d = 0; d < OUT_DIM; ++d) acc += W_t[d] * a[4 * OUT_DIM + d];
        consts[33] = acc;
    }
}

// ---------- kernel 2: z = h @ W_n ; s1[n]=z[n].a1 ; s2[n]=z[n].a2  (round-4 version, proven)
__global__ __launch_bounds__(256) void k_node(const float* __restrict__ h,
                                              const float* __restrict__ W_n,
                                              const float* __restrict__ a,
                                              float* __restrict__ z,
                                              float* __restrict__ s1,
                                              float* __restrict__ s2, int n) {
    __shared__ float hs[IN_DIM * 65];          // hs[k][r] at k*65+r, 33280 B
    __shared__ float s1p[4][64], s2p[4][64];
    int base = blockIdx.x * 64;

    for (int i = threadIdx.x; i < 64 * 32; i += 256) {
        int r = i >> 5;
        int c4 = i & 31;
        float4 v = make_float4(0.f, 0.f, 0.f, 0.f);
        if (base + r < n) v = ((const float4*)(h + (size_t)(base + r) * IN_DIM))[c4];
        int k0 = c4 * 4;
        hs[(k0 + 0) * 65 + r] = v.x;
        hs[(k0 + 1) * 65 + r] = v.y;
        hs[(k0 + 2) * 65 + r] = v.z;
        hs[(k0 + 3) * 65 + r] = v.w;
    }
    __syncthreads();

    int lane = threadIdx.x & 63;
    int w = __builtin_amdgcn_readfirstlane(threadIdx.x >> 6);
    int c0 = w * 16;
    int row = base + lane;

    float acc[16];
    #pragma unroll
    for (int j = 0; j < 16; ++j) acc[j] = 0.f;

    const float* __restrict__ Wslice = W_n + c0;
    #pragma unroll 4
    for (int k = 0; k < IN_DIM; ++k) {
        float hv = hs[k * 65 + lane];
        const float* __restrict__ Wr = Wslice + k * OUT_DIM;
        #pragma unroll
        for (int j = 0; j < 16; ++j) acc[j] = fmaf(hv, Wr[j], acc[j]);
    }

    float p1 = 0.f, p2 = 0.f;
    #pragma unroll
    for (int j = 0; j < 16; ++j) {
        p1 = fmaf(acc[j], a[c0 + j], p1);
        p2 = fmaf(acc[j], a[OUT_DIM + c0 + j], p2);
    }
    s1p[w][lane] = p1;
    s2p[w][lane] = p2;

    if (row < n) {
        float4* zp = (float4*)(z + (size_t)row * OUT_DIM + c0);
        zp[0] = make_float4(acc[0], acc[1], acc[2], acc[3]);
        zp[1] = make_float4(acc[4], acc[5], acc[6], acc[7]);
        zp[2] = make_float4(acc[8], acc[9], acc[10], acc[11]);
        zp[3] = make_float4(acc[12], acc[13], acc[14], acc[15]);
    }
    __syncthreads();
    if (threadIdx.x < 64 && base + (int)threadIdx.x < n) {
        int l = threadIdx.x;
        s1[base + l] = s1p[0][l] + s1p[1][l] + s1p[2][l] + s1p[3][l];
        s2[base + l] = s2p[0][l] + s2p[1][l] + s2p[2][l] + s2p[3][l];
    }
}

// ---------- kernel 3: degree histogram only (reads just dst)
__global__ __launch_bounds__(256) void k_count(const int* __restrict__ dst,
                                               int* __restrict__ deg, int E) {
    for (int e = blockIdx.x * blockDim.x + threadIdx.x; e < E;
         e += gridDim.x * blockDim.x)
        atomicAdd(deg + dst[e], 1);
}

// ---------- scan kernels: exclusive prefix sum of deg[0..n) -> off, cnt; off[n]=E
__global__ __launch_bounds__(256) void k_scan1(const int* __restrict__ deg,
                                               int* __restrict__ incl,
                                               int* __restrict__ partial, int n) {
    __shared__ int tmp[256];
    int i = blockIdx.x * 256 + threadIdx.x;
    int v = (i < n) ? deg[i] : 0;
    tmp[threadIdx.x] = v;
    __syncthreads();
    #pragma unroll
    for (int o = 1; o < 256; o <<= 1) {
        int t = (threadIdx.x >= o) ? tmp[threadIdx.x - o] : 0;
        __syncthreads();
        tmp[threadIdx.x] += t;
        __syncthreads();
    }
    if (i < n) incl[i] = tmp[threadIdx.x];
    if (threadIdx.x == 255) partial[blockIdx.x] = tmp[255];
}

__global__ __launch_bounds__(256) void k_scan2(int* __restrict__ partial, int nb) {
    __shared__ int tmp[256];
    int v = (threadIdx.x < nb) ? partial[threadIdx.x] : 0;
    tmp[threadIdx.x] = v;
    __syncthreads();
    #pragma unroll
    for (int o = 1; o < 256; o <<= 1) {
        int t = (threadIdx.x >= o) ? tmp[threadIdx.x - o] : 0;
        __syncthreads();
        tmp[threadIdx.x] += t;
        __syncthreads();
    }
    if (threadIdx.x < nb) partial[threadIdx.x] = tmp[threadIdx.x] - v;  // exclusive
}

__global__ __launch_bounds__(256) void k_scan3(const int* __restrict__ deg,
                                               const int* __restrict__ incl,
                                               const int* __restrict__ partial,
                                               int* __restrict__ off,
                                               int* __restrict__ cnt, int n, int E) {
    int i = blockIdx.x * 256 + threadIdx.x;
    if (i < n) {
        int o = incl[i] - deg[i] + partial[i >> 8];
        off[i] = o;
        cnt[i] = o;
    }
    if (i == 0) off[n] = E;
}

// ---------- kernel 4: fused logit compute + permute into dst-grouped (src,logit) pairs
__global__ __launch_bounds__(256) void k_fill(const float* __restrict__ rel,
                                              const float* __restrict__ score,
                                              const float* __restrict__ ts,
                                              const int* __restrict__ src,
                                              const int* __restrict__ dst,
                                              const float* __restrict__ s1,
                                              const float* __restrict__ s2,
                                              const float* __restrict__ consts,
                                              int* __restrict__ cnt,
                                              int2* __restrict__ pedge, int E) {
    __shared__ float wra3[REL_DIM];
    __shared__ float c45[2];
    if (threadIdx.x < REL_DIM) wra3[threadIdx.x] = consts[threadIdx.x];
    if (threadIdx.x == 32) c45[0] = consts[32];
    if (threadIdx.x == 33) c45[1] = consts[33];
    __syncthreads();
    for (int e = blockIdx.x * blockDim.x + threadIdx.x; e < E;
         e += gridDim.x * blockDim.x) {
        const float4* r4 = (const float4*)(rel + (size_t)e * REL_DIM);
        float acc = 0.f;
        #pragma unroll
        for (int j = 0; j < REL_DIM / 4; ++j) {
            float4 v = r4[j];
            acc += v.x * wra3[4 * j] + v.y * wra3[4 * j + 1] +
                   v.z * wra3[4 * j + 2] + v.w * wra3[4 * j + 3];
        }
        int s = src[e], d = dst[e];
        float lg = s1[s] + s2[d] + acc + score[e] * c45[0] + ts[e] * c45[1];
        lg = (lg >= 0.f) ? lg : NEG_SLOPE * lg;
        int pos = atomicAdd(cnt + d, 1);
        pedge[pos] = make_int2(s, __float_as_int(lg));
    }
}

// ---------- kernel 5: one wave per node; register-cached softmax + 4-edge-parallel gather
__global__ __launch_bounds__(256) void k_out(const int* __restrict__ off,
                                             const int2* __restrict__ pedge,
                                             const float* __restrict__ z,
                                             float* __restrict__ out, int n) {
    int lane = threadIdx.x & 63;
    int wave = (blockIdx.x * blockDim.x + threadIdx.x) >> 6;
    int nwaves = (gridDim.x * blockDim.x) >> 6;
    int eg = lane >> 4;        // edge group 0..3
    int dl = lane & 15;        // dim lane: dims [4*dl, 4*dl+4)
    for (int node = wave; node < n; node += nwaves) {
        int start = off[node], end = off[node + 1];
        int deg = end - start;
        float4 acc = make_float4(0.f, 0.f, 0.f, 0.f);
        if (deg > 0 && deg <= 64) {
            // common path: whole segment cached in one register per lane
            int2 pe = make_int2(0, (int)0xff800000u);  // src=0, logit=-inf
            if (lane < deg) pe = pedge[start + lane];
            float v = __int_as_float(pe.y);
            float m = v;
            #pragma unroll
            for (int o = 32; o > 0; o >>= 1) m = fmaxf(m, __shfl_xor(m, o, 64));
            float ex = __expf(v - m);                  // masked lanes: exp(-inf)=0
            float ssum = ex;
            #pragma unroll
            for (int o = 32; o > 0; o >>= 1) ssum += __shfl_xor(ssum, o, 64);
            float alpha = ex * (1.0f / ssum);          // per-lane weight for edge start+lane
            for (int j0 = 0; j0 < deg; j0 += 4) {
                int j = j0 + eg;
                int jc = (j < 64) ? j : 63;
                float wj = __shfl(alpha, jc, 64);
                int  sj = __shfl(pe.x, jc, 64);
                if (j < deg) {
                    float4 zv = ((const float4*)(z + (size_t)sj * OUT_DIM))[dl];
                    acc.x = fmaf(wj, zv.x, acc.x);
                    acc.y = fmaf(wj, zv.y, acc.y);
                    acc.z = fmaf(wj, zv.z, acc.z);
                    acc.w = fmaf(wj, zv.w, acc.w);
                }
            }
        } else if (deg > 64) {
            // generic path
            float m = -3.4e38f;
            for (int j = start + lane; j < end; j += 64)
                m = fmaxf(m, __int_as_float(pedge[j].y));
            #pragma unroll
            for (int o = 32; o > 0; o >>= 1) m = fmaxf(m, __shfl_xor(m, o, 64));
            float ssum = 0.f;
            for (int j = start + lane; j < end; j += 64)
                ssum += __expf(__int_as_float(pedge[j].y) - m);
            #pragma unroll
            for (int o = 32; o > 0; o >>= 1) ssum += __shfl_xor(ssum, o, 64);
            float inv = 1.0f / ssum;
            for (int j0 = start; j0 < end; j0 += 4) {
                int j = j0 + eg;
                if (j < end) {
                    int2 pe = pedge[j];
                    float wj = __expf(__int_as_float(pe.y) - m) * inv;
                    float4 zv = ((const float4*)(z + (size_t)pe.x * OUT_DIM))[dl];
                    acc.x = fmaf(wj, zv.x, acc.x);
                    acc.y = fmaf(wj, zv.y, acc.y);
                    acc.z = fmaf(wj, zv.z, acc.z);
                    acc.w = fmaf(wj, zv.w, acc.w);
                }
            }
        }
        // reduce across the 4 edge groups (xor 16, 32), then 16 lanes store float4
        #pragma unroll
        for (int o = 16; o <= 32; o <<= 1) {
            acc.x += __shfl_xor(acc.x, o, 64);
            acc.y += __shfl_xor(acc.y, o, 64);
            acc.z += __shfl_xor(acc.z, o, 64);
            acc.w += __shfl_xor(acc.w, o, 64);
        }
        if (eg == 0) ((float4*)(out + (size_t)node * OUT_DIM))[dl] = acc;
    }
}

extern "C" void kernel_launch(void* const* d_in, const int* in_sizes, int n_in,
                              void* d_out, int out_size, void* d_ws, size_t ws_size,
                              hipStream_t stream) {
    const float* h         = (const float*)d_in[0];
    const float* relation  = (const float*)d_in[1];
    const float* score     = (const float*)d_in[2];
    const float* timestamp = (const float*)d_in[3];
    const int*   src       = (const int*)d_in[4];
    const int*   dst       = (const int*)d_in[5];
    const float* W_n       = (const float*)d_in[6];
    const float* W_r       = (const float*)d_in[7];
    const float* W_s       = (const float*)d_in[8];
    const float* W_t       = (const float*)d_in[9];
    const float* a         = (const float*)d_in[10];

    int n = in_sizes[0] / IN_DIM;   // 50000
    int E = in_sizes[4];            // 800000
    int nb1 = (n + 255) / 256;      // 196 scan blocks

    // workspace layout (floats); pedge offset is 8B-aligned by construction
    float* ws      = (float*)d_ws;
    float* z       = ws;                                  // n*64
    float* s1      = z + (size_t)n * OUT_DIM;             // n
    float* s2      = s1 + n;                              // n
    float* consts  = s2 + n;                              // 64 (34 used)
    int2*  pedge   = (int2*)(consts + 64);                // E pairs
    int*   deg     = (int*)(pedge + E);                   // n
    int*   incl    = deg + n;                             // n
    int*   off     = incl + n;                            // n+1
    int*   cnt     = off + n + 1;                         // n
    int*   partial = cnt + n;                             // nb1 (<=256)

    float* out = (float*)d_out;

    hipMemsetAsync(deg, 0, (size_t)n * sizeof(int), stream);

    k_consts<<<1, 64, 0, stream>>>(W_r, W_s, W_t, a, consts);
    k_node<<<(n + 63) / 64, 256, 0, stream>>>(h, W_n, a, z, s1, s2, n);
    k_count<<<2048, 256, 0, stream>>>(dst, deg, E);
    k_scan1<<<nb1, 256, 0, stream>>>(deg, incl, partial, n);
    k_scan2<<<1, 256, 0, stream>>>(partial, nb1);
    k_scan3<<<nb1, 256, 0, stream>>>(deg, incl, partial, off, cnt, n, E);
    k_fill<<<2048, 256, 0, stream>>>(relation, score, timestamp, src, dst,
                                     s1, s2, consts, cnt, pedge, E);
    k_out<<<(n + 3) / 4, 256, 0, stream>>>(off, pedge, z, out, n);
}